// Round 5
// baseline (100.052 us; speedup 1.0000x reference)
//
#include <hip/hip_runtime.h>

#define ENT_GRID 16
#define ENT_DIM  64
#define EMB      1024   // ENT_GRID * ENT_DIM
#define LN_EPS   1e-5f

// ---------- sort-by-relation-id machinery (device-side, capture-safe) ----------

__global__ void zero_hist_kernel(int* __restrict__ hist, int n) {
    int i = blockIdx.x * blockDim.x + threadIdx.x;
    if (i < n) hist[i] = 0;
}

__global__ void hist_kernel(const int* __restrict__ ids, int* __restrict__ hist, int B) {
    int i = blockIdx.x * blockDim.x + threadIdx.x;
    if (i < B) atomicAdd(&hist[ids[i]], 1);
}

__global__ __launch_bounds__(1024)
void scan_kernel(const int* __restrict__ hist, int* __restrict__ cursor, int n) {
    const int t = threadIdx.x;
    const int ITEMS = (n + 1023) / 1024;
    int vals[8];
    int lsum = 0;
#pragma unroll
    for (int k = 0; k < 8; ++k) {
        int i = t * ITEMS + k;
        int v = (k < ITEMS && i < n) ? hist[i] : 0;
        vals[k] = v;
        lsum += v;
    }
    __shared__ int s[1024];
    s[t] = lsum;
    __syncthreads();
    for (int off = 1; off < 1024; off <<= 1) {
        int v = (t >= off) ? s[t - off] : 0;
        __syncthreads();
        s[t] += v;
        __syncthreads();
    }
    int run = s[t] - lsum;
#pragma unroll
    for (int k = 0; k < 8; ++k) {
        int i = t * ITEMS + k;
        if (k < ITEMS && i < n) cursor[i] = run;
        run += vals[k];
    }
}

__global__ void scatter_kernel(const int* __restrict__ ids, int* __restrict__ cursor,
                               int* __restrict__ perm, int B) {
    int i = blockIdx.x * blockDim.x + threadIdx.x;
    if (i < B) {
        int pos = atomicAdd(&cursor[ids[i]], 1);
        perm[pos] = i;
    }
    // after: cursor[r] == END offset of group r; start = cursor[r] - hist[r]
}

__device__ __forceinline__ float dot4(float4 a, float4 b) {
    return a.x * b.x + a.y * b.y + a.z * b.z + a.w * b.w;
}

// ---------- main kernel: one block per relation, 1024 threads, 1 output/thread ----------
// Thread t owns output column t: tran row t (16 floats = 16 VGPR), bias/LN scalars.
// ~50 VGPR total -> <=64 tier -> 32 waves/CU (2 blocks co-resident).
// Per row: ds_write emb; issue NEXT row's emb load (stays in flight across the
// lgkm-only barriers); dot; wave shfl-reduce; cross-wave LDS reduce; LN; store.
__global__ __launch_bounds__(1024, 8)
void wproj_group_kernel(const float* __restrict__ ent_emb,
                        const float* __restrict__ rel_tran,
                        const float* __restrict__ rel_bias,
                        const float* __restrict__ ln_w,
                        const float* __restrict__ ln_b,
                        const int*   __restrict__ hist,
                        const int*   __restrict__ cursor_end,
                        const int*   __restrict__ perm,
                        float* __restrict__ out) {
    const int r   = blockIdx.x;
    const int cnt = hist[r];
    if (cnt == 0) return;
    const int start = cursor_end[r] - cnt;
    const int t = threadIdx.x;
    const int w = t >> 6;

    // this thread's tran row (16 floats), bias + LN params (scalars)
    const float4* __restrict__ tr4 = reinterpret_cast<const float4*>(
        rel_tran + (size_t)r * (ENT_DIM * ENT_GRID * ENT_GRID) + (size_t)t * ENT_GRID);
    const float4 t0 = tr4[0], t1 = tr4[1], t2 = tr4[2], t3 = tr4[3];
    const float bv  = rel_bias[(size_t)r * EMB + t];
    const float lwv = ln_w[t];
    const float lbv = ln_b[t];

    __shared__ __align__(16) float se[2][EMB];       // double-buffered emb row
    __shared__ __align__(16) float wred[2][2][16];   // [buf][sum|sq][wave]

    int   bcur = perm[start];
    float vcur = ent_emb[(size_t)bcur * EMB + t];

    for (int j = 0; j < cnt; ++j) {
        const int jb = j & 1;
        se[jb][t] = vcur;                       // compiler waits vcur (counted vmcnt)

        int bnext = 0; float vnext = 0.0f;
        if (j + 1 < cnt) {                      // depth-1 prefetch: stays in flight
            bnext = perm[start + j + 1];
            vnext = ent_emb[(size_t)bnext * EMB + t];
        }

        // publish se[jb]; waits LDS/SMEM only — prefetch + stores NOT drained
        asm volatile("s_waitcnt lgkmcnt(0)\n\ts_barrier" ::: "memory");

        const float4* __restrict__ er =
            reinterpret_cast<const float4*>(&se[jb][(t >> 4) * ENT_GRID]);
        const float x = bv + dot4(t0, er[0]) + dot4(t1, er[1])
                           + dot4(t2, er[2]) + dot4(t3, er[3]);

        float s = x, ss = x * x;
#pragma unroll
        for (int off = 32; off > 0; off >>= 1) {
            s  += __shfl_xor(s, off, 64);
            ss += __shfl_xor(ss, off, 64);
        }
        if ((t & 63) == 0) { wred[jb][0][w] = s; wred[jb][1][w] = ss; }

        // publish wred; also retires all readers of se[jb^1] for next overwrite
        asm volatile("s_waitcnt lgkmcnt(0)\n\ts_barrier" ::: "memory");

        float tsum = 0.0f, tsq = 0.0f;
        const float4* __restrict__ ps = reinterpret_cast<const float4*>(&wred[jb][0][0]);
        const float4* __restrict__ pq = reinterpret_cast<const float4*>(&wred[jb][1][0]);
#pragma unroll
        for (int q = 0; q < 4; ++q) {
            const float4 a = ps[q];
            const float4 c = pq[q];
            tsum += a.x + a.y + a.z + a.w;
            tsq  += c.x + c.y + c.z + c.w;
        }
        const float mu   = tsum * (1.0f / (float)EMB);
        const float var  = tsq * (1.0f / (float)EMB) - mu * mu;
        const float rstd = rsqrtf(var + LN_EPS);

        out[(size_t)bcur * EMB + t] = (x - mu) * rstd * lwv + lbv;  // fire & forget

        bcur = bnext;
        vcur = vnext;
    }
}

extern "C" void kernel_launch(void* const* d_in, const int* in_sizes, int n_in,
                              void* d_out, int out_size, void* d_ws, size_t ws_size,
                              hipStream_t stream) {
    const float* ent_emb  = (const float*)d_in[0];
    const int*   proj_ids = (const int*)  d_in[1];
    const float* rel_tran = (const float*)d_in[2];
    const float* rel_bias = (const float*)d_in[3];
    const float* ln_w     = (const float*)d_in[4];
    const float* ln_b     = (const float*)d_in[5];
    float* out = (float*)d_out;

    const int B  = in_sizes[1];                                     // 8192
    const int NR = in_sizes[2] / (ENT_DIM * ENT_GRID * ENT_GRID);   // 5000

    int* w      = (int*)d_ws;
    int* hist   = w;            // [NR]
    int* cursor = w + NR;       // [NR]
    int* perm   = w + 2 * NR;   // [B]

    zero_hist_kernel<<<(NR + 255) / 256, 256, 0, stream>>>(hist, NR);
    hist_kernel<<<(B + 255) / 256, 256, 0, stream>>>(proj_ids, hist, B);
    scan_kernel<<<1, 1024, 0, stream>>>(hist, cursor, NR);
    scatter_kernel<<<(B + 255) / 256, 256, 0, stream>>>(proj_ids, cursor, perm, B);

    wproj_group_kernel<<<NR, 1024, 0, stream>>>(ent_emb, rel_tran, rel_bias, ln_w, ln_b,
                                                hist, cursor, perm, out);
}